// Round 7
// baseline (92.583 us; speedup 1.0000x reference)
//
#include <hip/hip_runtime.h>

#define BB 4
#define HH 480
#define WW 640

// det of general 3x3
__device__ __forceinline__ double det3d(double a, double b, double c,
                                        double d, double e, double f,
                                        double g, double h, double i) {
    return a * (e * i - f * h) - b * (d * i - f * g) + c * (d * h - e * g);
}

// det of symmetric 3x3 [[a,b,c],[b,e,f],[c,f,i]]
__device__ __forceinline__ double sdet3d(double a, double b, double c,
                                         double e, double f, double i) {
    return a * (e * i - f * f) + b * (2.0 * c * f - b * i) - c * c * e;
}

// cheap reciprocal of a double: f32 seed, ~1e-5 relative error.
// Valid where the use is scale-invariant or self-correcting (Newton).
__device__ __forceinline__ double crcp(double d) {
    return (double)__builtin_amdgcn_rcpf((float)d);
}

// block=256, min 8 waves/EU: keeps 8 waves/SIMD occupancy while raising the
// compiler's VGPR budget to 64 (was 40 -> over-throttled ILP in f64 trees).
__global__ __launch_bounds__(256, 8) void d2n_kernel(const float* __restrict__ pts,
                                                     float* __restrict__ out) {
    int idx = blockIdx.x * 256 + threadIdx.x;
    if (idx >= BB * HH * WW) return;
    int x = idx % WW;
    int t1 = idx / WW;
    int y = t1 % HH;
    int b = t1 / HH;

    const size_t HW = (size_t)HH * WW;
    const float* xs = pts + ((size_t)b * 3 + 0) * HW;
    const float* ys = pts + ((size_t)b * 3 + 1) * HW;
    const float* zs = pts + ((size_t)b * 3 + 2) * HW;
    int o = y * WW + x;

    float px[9], py[9], pz[9];
    float w9[9];

    bool edge = (x == 0) | (x == WW - 1) | (y == 0) | (y == HH - 1);
    if (!__any(edge)) {
        // ---- interior wave (~97%): constant offsets off one base pointer;
        //      loads become global_load_dword with immediate offsets ----
        const float* cxp = xs + o;
        const float* cyp = ys + o;
        const float* czp = zs + o;
#pragma unroll
        for (int i = 0; i < 9; ++i) {
            int off = (i / 3 - 1) * WW + (i % 3 - 1);
            px[i] = cxp[off];
            py[i] = cyp[off];
            pz[i] = czp[off];
            w9[i] = (pz[i] > 0.0f && pz[i] < 10.0f) ? 1.0f : 0.0f;
        }
    } else {
        // ---- border wave: clamped addresses, validity = in-bounds & z-range ----
        int row[3], col[3];
        bool rin[3], cin[3];
#pragma unroll
        for (int k = 0; k < 3; ++k) {
            int yy = y + k - 1, xx = x + k - 1;
            rin[k] = (unsigned)yy < HH;
            cin[k] = (unsigned)xx < WW;
            row[k] = min(max(yy, 0), HH - 1) * WW;
            col[k] = min(max(xx, 0), WW - 1);
        }
#pragma unroll
        for (int i = 0; i < 9; ++i) {
            int r = i / 3, c = i % 3;
            int oo = row[r] + col[c];
            px[i] = xs[oo];
            py[i] = ys[oo];
            pz[i] = zs[oo];
            w9[i] = (rin[r] & cin[c]) && pz[i] > 0.0f && pz[i] < 10.0f ? 1.0f : 0.0f;
        }
    }

    // ---- Gram accumulation (f32, matches reference AtA precision) ----
    float sxx = 0.f, sxy = 0.f, sxz = 0.f, sx = 0.f;
    float syy = 0.f, syz = 0.f, sy = 0.f;
    float szz = 0.f, sz = 0.f, cnt = 0.f;
#pragma unroll
    for (int i = 0; i < 9; ++i) {
        float w = w9[i];
        float qx = px[i] * w, qy = py[i] * w, qz = pz[i] * w;
        sxx += qx * px[i]; sxy += qx * py[i]; sxz += qx * pz[i]; sx += qx;
        syy += qy * py[i]; syz += qy * pz[i]; sy += qy;
        szz += qz * pz[i]; sz += qz;
        cnt += w;
    }

    // ---- Promote to f64; scale by ~1/trace (uniform scale: eigvec-invariant) ----
    double tr = (double)sxx + (double)syy + (double)szz + (double)cnt;
    double it = crcp(tr);
    double m00 = sxx * it, m01 = sxy * it, m02 = sxz * it, m03 = sx * it;
    double m11 = syy * it, m12 = syz * it, m13 = sy * it;
    double m22 = szz * it, m23 = sz * it, m33 = cnt * it;

    // ---- Characteristic polynomial p(l)=l^4 - e1 l^3 + e2 l^2 - e3 l + e4
    //      (f64: coefficients are differences of products -> cancellation) ----
    double e1 = m00 + m11 + m22 + m33;
    double e2 = (m00 * m11 - m01 * m01) + (m00 * m22 - m02 * m02) +
                (m00 * m33 - m03 * m03) + (m11 * m22 - m12 * m12) +
                (m11 * m33 - m13 * m13) + (m22 * m33 - m23 * m23);
    double P0 = sdet3d(m11, m12, m13, m22, m23, m33);
    double P1 = sdet3d(m00, m02, m03, m22, m23, m33);
    double P2 = sdet3d(m00, m01, m03, m11, m13, m33);
    double P3 = sdet3d(m00, m01, m02, m11, m12, m22);
    double e3 = P0 + P1 + P2 + P3;
    double e4 = m00 * P0
              - m01 * det3d(m01, m12, m13, m02, m22, m23, m03, m23, m33)
              + m02 * det3d(m01, m11, m13, m02, m12, m23, m03, m13, m33)
              - m03 * det3d(m01, m11, m12, m02, m12, m22, m03, m13, m23);

    // ---- Newton toward smallest eigenvalue: 8 f32 warm + 5 f64 polish.
    //      Near-double roots converge linearly (rate 1/2) until within-gap:
    //      do NOT trim iteration counts (R2 post-mortem). ----
    float e1f = (float)e1, e2f = (float)e2, e3f = (float)e3, e4f = (float)e4;
    float t31f = 3.0f * e1f, t22f = 2.0f * e2f;
    float lf = 0.0f;
#pragma unroll
    for (int itn = 0; itn < 8; ++itn) {
        float p  = (((lf - e1f) * lf + e2f) * lf - e3f) * lf + e4f;
        float dp = ((4.0f * lf - t31f) * lf + t22f) * lf - e3f;
        dp = fminf(dp, -1e-30f);
        lf = lf - p * __builtin_amdgcn_rcpf(dp);
        lf = fminf(fmaxf(lf, 0.0f), 0.26f);
    }
    double t31 = 3.0 * e1, t22 = 2.0 * e2;
    double lam = (double)lf;
#pragma unroll
    for (int itn = 0; itn < 5; ++itn) {
        double p  = (((lam - e1) * lam + e2) * lam - e3) * lam + e4;
        double dp = ((4.0 * lam - t31) * lam + t22) * lam - e3;
        dp = fmin(dp, -1e-30);
        lam = lam - p * crcp(dp);
        lam = fmin(fmax(lam, 0.0), 0.26);
    }

    // ---- Adjugate of (M - lam I): rank-1 = c * v1 v1^T at converged lam ----
    double d0 = m00 - lam, d1 = m11 - lam, d2 = m22 - lam, d3 = m33 - lam;
    double C00 =  sdet3d(d1, m12, m13, d2, m23, d3);
    double C11 =  sdet3d(d0, m02, m03, d2, m23, d3);
    double C22 =  sdet3d(d0, m01, m03, d1, m13, d3);
    double C33 =  sdet3d(d0, m01, m02, d1, m12, d2);
    double C01 = -det3d(m01, m12, m13, m02, d2, m23, m03, m23, d3);
    double C02 =  det3d(m01, d1, m13, m02, m12, m23, m03, m13, d3);
    double C03 = -det3d(m01, d1, m12, m02, m12, d2, m03, m13, m23);
    double C12 = -det3d(d0, m01, m03, m02, m12, m23, m03, m13, d3);
    double C13 =  det3d(d0, m01, m02, m02, m12, d2, m03, m13, m23);
    double C23 = -det3d(d0, m01, m02, m01, d1, m12, m03, m13, m23);

    // pick column with largest |diagonal cofactor| (= largest v1 comp^2)
    double best = fabs(C00);
    double vx = C00, vy = C01, vz = C02, vd = C00;
    double a1 = fabs(C11);
    if (a1 > best) { best = a1; vx = C01; vy = C11; vz = C12; vd = C11; }
    double a2 = fabs(C22);
    if (a2 > best) { best = a2; vx = C02; vy = C12; vz = C22; vd = C22; }
    double a3 = fabs(C33);
    if (a3 > best) { best = a3; vx = C03; vy = C13; vz = C23; vd = C33; }

    // scale column by ~1/vd (uniform scale: error cancels in normalization)
    double sc = crcp(vd);
    float fx = (float)(vx * sc), fy = (float)(vy * sc), fz = (float)(vz * sc);

    float nd = fx * fx + fy * fy + fz * fz;
    float inv = __builtin_amdgcn_rsqf(fmaxf(nd, 1e-30f));
    float nx = fx * inv, ny = fy * inv, nz = fz * inv;

    float cx = px[4], cy = py[4], cz = pz[4];
    float dot = nx * cx + ny * cy + nz * cz;
    float sgn = (dot > 0.0f) ? 1.0f : ((dot < 0.0f) ? -1.0f : 0.0f);
    nx *= sgn; ny *= sgn; nz *= sgn;

    out[((size_t)b * 3 + 0) * HW + o] = nx;
    out[((size_t)b * 3 + 1) * HW + o] = ny;
    out[((size_t)b * 3 + 2) * HW + o] = nz;

    bool cvalid = (cz > 0.0f && cz < 10.0f);
    bool m = cvalid && (cnt >= 4.0f) && (nx * nx + ny * ny + nz * nz > 0.25f);
    out[(size_t)BB * 3 * HW + (size_t)b * HW + o] = m ? 1.0f : 0.0f;
}

extern "C" void kernel_launch(void* const* d_in, const int* in_sizes, int n_in,
                              void* d_out, int out_size, void* d_ws, size_t ws_size,
                              hipStream_t stream) {
    const float* pts = (const float*)d_in[0];
    float* out = (float*)d_out;
    int total = BB * HH * WW;
    d2n_kernel<<<(total + 255) / 256, 256, 0, stream>>>(pts, out);
}